// Round 11
// baseline (250.620 us; speedup 1.0000x reference)
//
#include <hip/hip_runtime.h>

// BmmEnsemble: species-routed 4x8 MLP ensemble (384->160->128->96->1, CELU 0.1),
// mean over 8 models, global sum -> scalar.
// R16: 16 WAVES/CU (the last unisolated lever). R15 rejected (absmax 4.0:
// atom-window clobber bug; also L2 thrash from per-model aevf re-reads).
// m97 comparison: structurally identical slot (MFMA+ds_read+gload+barrier)
// runs 740cy/CU-slot at 12 waves/CU vs our 1400cy at 8 waves/CU -- every
// good R-variant had exactly 8 waves/CU. This round: R12's exact geometry
// (784 blocks, 92 x 8KB chunk-slots, counted vmcnt, aevb routed-bf16 atoms)
// but 512-thread blocks (8 waves) with MT=1 (16 atoms/wave, ABLK still 128).
// hbuf [8][16][168] keeps LDS at 71.7KB -> 2 blocks/CU -> 16 waves/CU.
// Per-wave regs halve (a1 48 + C 40); launch_bounds(512,4) caps VGPR 128.
// Each wave stages 1KB/chunk (vmcnt(1)); 8 MFMA + 8 ds_read_b128 per chunk.

#define NSP 4
#define NMODELS 8
#define MSPLIT 2
#define MPB (NMODELS / MSPLIT)       // 4 models per block
#define NATOMS 50000
#define NPER (NATOMS / NSP)          // 12500
#define NPAD 12544                   // 98*128 padded rows per species
#define D0 384
#define D1 160
#define D2 128
#define D3 96
#define NRBLK ((NATOMS + 255) / 256) // 196
#define ABLK 128                     // 8 waves x 16 atoms
#define BPS ((NPER + ABLK - 1) / ABLK) // 98 blocks per species
#define FRAGS_SM 184                  // 120 (W1) + 40 (W2) + 24 (W3) fragments
#define CHUNKS_M 23                   // 184 frags / 8 per chunk
#define TOT_CHUNKS (MPB * CHUNKS_M)   // 92 chunks per block

typedef float f32x4 __attribute__((ext_vector_type(4)));
typedef __bf16 bf16x8 __attribute__((ext_vector_type(8)));

#define MFMA16(a, b, c) __builtin_amdgcn_mfma_f32_16x16x32_bf16((a), (b), (c), 0, 0, 0)

// ---- workspace layout (bytes) ----
#define PALL_BYTES ((size_t)NSP * NMODELS * FRAGS_SM * 1024)
#define PBIAS_OFF PALL_BYTES
#define PBIAS_BYTES ((size_t)NSP * NMODELS * 512 * 2)   // 1KB per (s,m)
#define ORDER_OFF (PBIAS_OFF + PBIAS_BYTES)
#define BCNT_OFF (ORDER_OFF + (size_t)NATOMS * 4)
#define BPFX_OFF (BCNT_OFF + (size_t)NRBLK * NSP * 4)
#define BASE_OFF (BPFX_OFF + (size_t)NRBLK * NSP * 4)
#define AEVB_OFF (BASE_OFF + 1024)                      // 64B-aligned
#define AEVB_BYTES ((size_t)NSP * NPAD * D0 * 2)        // 38.5 MB bf16

static __device__ __forceinline__ unsigned short bfbits(float f) {
  __bf16 h = (__bf16)f;
  return __builtin_bit_cast(unsigned short, h);
}

static __device__ __forceinline__ float celu01(float x) {
  // celu(x, alpha=0.1) = max(x,0) + min(0, 0.1*(exp(x/0.1)-1))
  return fmaxf(x, 0.f) + 0.1f * fminf(0.f, __expf(x * 10.f) - 1.f);
}

// async global->LDS, 16 B per lane; LDS dest = wave-uniform base + lane*16
static __device__ __forceinline__ void gload16(const void* g, void* l) {
  __builtin_amdgcn_global_load_lds(
      (const __attribute__((address_space(1))) unsigned int*)g,
      (__attribute__((address_space(3))) unsigned int*)l, 16, 0, 0);
}

// ---------------- routing ----------------
__global__ __launch_bounds__(256) void count_kernel(const int* __restrict__ species,
                                                    int* __restrict__ bcnt) {
  __shared__ int cnt[NSP];
  int t = threadIdx.x;
  if (t < NSP) cnt[t] = 0;
  __syncthreads();
  int i = blockIdx.x * 256 + t;
  if (i < NATOMS) atomicAdd(&cnt[species[i]], 1);
  __syncthreads();
  if (t < NSP) bcnt[blockIdx.x * NSP + t] = cnt[t];
}

__global__ __launch_bounds__(256) void scan_kernel(const int* __restrict__ bcnt,
                                                   int* __restrict__ bpfx,
                                                   int* __restrict__ base) {
  int w = threadIdx.x >> 6;
  int lane = threadIdx.x & 63;
  __shared__ int totals[NSP];
  int carry = 0;
  for (int c = 0; c < (NRBLK + 63) / 64; ++c) {
    int idx = c * 64 + lane;
    int v = (idx < NRBLK) ? bcnt[idx * NSP + w] : 0;
    int incl = v;
    for (int off = 1; off < 64; off <<= 1) {
      int tv = __shfl_up(incl, off);
      if (lane >= off) incl += tv;
    }
    if (idx < NRBLK) bpfx[idx * NSP + w] = carry + incl - v;
    carry += __shfl(incl, 63);
  }
  if (lane == 0) totals[w] = carry;
  __syncthreads();
  if (threadIdx.x == 0) {
    int run = 0;
    for (int s = 0; s < NSP; ++s) { base[s] = run; run += totals[s]; }
  }
}

__global__ __launch_bounds__(256) void route_kernel(const int* __restrict__ species,
                                                    const int* __restrict__ bpfx,
                                                    const int* __restrict__ base,
                                                    int* __restrict__ order) {
  __shared__ int sp[256];
  int t = threadIdx.x;
  int i = blockIdx.x * 256 + t;
  sp[t] = (i < NATOMS) ? species[i] : -1;
  __syncthreads();
  if (i < NATOMS) {
    int s = sp[t];
    int rank = 0;
    for (int j = 0; j < t; ++j) rank += (sp[j] == s) ? 1 : 0;
    order[base[s] + bpfx[blockIdx.x * NSP + s] + rank] = i;
  }
}

// ---------------- routed bf16 aev pre-pack ----------------
// aevb[s*NPAD + slot][k] = bf16(aev[order[s*NPER+slot]][k]); pad rows zeroed.
__global__ __launch_bounds__(256) void aev_pack(const float* __restrict__ aev,
                                                const int* __restrict__ order,
                                                unsigned short* __restrict__ aevb) {
  int tid = blockIdx.x * 256 + threadIdx.x;   // NSP*NPAD*48 total
  const int perRow = D0 / 8;                  // 48
  int row = tid / perRow;
  int seg = tid - row * perRow;
  if (row >= NSP * NPAD) return;
  int s = row / NPAD;
  int slot = row - s * NPAD;
  unsigned short o[8];
  if (slot < NPER) {
    int src = order[s * NPER + slot];
    const float4* q = (const float4*)(aev + (size_t)src * D0 + seg * 8);
    float4 v0 = q[0], v1 = q[1];
    o[0] = bfbits(v0.x); o[1] = bfbits(v0.y); o[2] = bfbits(v0.z); o[3] = bfbits(v0.w);
    o[4] = bfbits(v1.x); o[5] = bfbits(v1.y); o[6] = bfbits(v1.z); o[7] = bfbits(v1.w);
  } else {
#pragma unroll
    for (int e = 0; e < 8; ++e) o[e] = 0;
  }
  *(int4*)(aevb + (size_t)row * D0 + seg * 8) = *(const int4*)o;
}

// ---------------- weight pre-pack into contiguous B-fragment stream ----------------
// pAll: per (s,m) block of FRAGS_SM fragments (1 KB each). Frag order within a
// layer: f = kf*NT + nt. Lane l, bf16 elem e: k = kf*32 + 8*(l>>4) + e ; n = nt*16 + (l&15).
__global__ __launch_bounds__(256) void pack_kernel(const float* __restrict__ W,
                                                   unsigned* __restrict__ dst,
                                                   int K, int N, int NT, int fragBase,
                                                   int total) {
  int tid = blockIdx.x * 256 + threadIdx.x;
  if (tid >= total) return;
  int per_sm = K * N / 2;            // dwords per (s,m)
  int smi = tid / per_sm;
  int rem = tid - smi * per_sm;
  int frag = rem >> 8;               // 256 dwords per fragment
  int wi = rem & 255;
  int l = wi >> 2, d = wi & 3;
  int kf = frag / NT;
  int nt = frag - kf * NT;
  int k = kf * 32 + ((l >> 4) << 3) + 2 * d;
  int n = nt * 16 + (l & 15);
  const float* p = W + ((size_t)smi * K + k) * N + n;
  unsigned lo = bfbits(p[0]);
  unsigned hi = bfbits(p[N]);
  dst[((size_t)smi * FRAGS_SM + fragBase + frag) * 256 + wi] = lo | (hi << 16);
}

// param pack: per (s,m) record of 512 shorts:
// [0:160) b1 bf16 | [160:288) b2 bf16 | [288:384) b3 bf16 | [384:480) W4 bf16 |
// [480:482) b4 as f32 bit halves | rest 0
__global__ __launch_bounds__(256) void param_pack(const float* __restrict__ b1,
                                                  const float* __restrict__ b2,
                                                  const float* __restrict__ b3,
                                                  const float* __restrict__ W4,
                                                  const float* __restrict__ b4,
                                                  unsigned short* __restrict__ dst) {
  int i = blockIdx.x * 256 + threadIdx.x;
  if (i >= NSP * NMODELS * 512) return;
  int smi = i >> 9, o = i & 511;
  unsigned short v = 0;
  if (o < 160) v = bfbits(b1[smi * 160 + o]);
  else if (o < 288) v = bfbits(b2[smi * 128 + (o - 160)]);
  else if (o < 384) v = bfbits(b3[smi * 96 + (o - 288)]);
  else if (o < 480) v = bfbits(W4[smi * 96 + (o - 384)]);
  else if (o < 482) {
    unsigned u = __builtin_bit_cast(unsigned, b4[smi]);
    v = (unsigned short)((o == 480) ? (u & 0xffffu) : (u >> 16));
  }
  dst[i] = v;
}

// ---------------- fused MLP (8 waves, MT=1, counted vmcnt(1)) ----------------
// steady state: wait vmcnt(1) [chunk t's load done; t+1's in flight],
// barrier (all waves' chunk-t loads landed), issue chunk t+2.
#define CHUNK_HDR()                                                      \
  do {                                                                   \
    asm volatile("s_waitcnt vmcnt(1)" ::: "memory");                     \
    __builtin_amdgcn_s_barrier();                                        \
    gload16(wsrc + (size_t)tn * 8192, (char*)stage + wb_off + w * 1024); \
    tn = (tn + 1 == TOT_CHUNKS) ? 0 : (tn + 1);                          \
    wb_off = (wb_off == 16384u) ? 0u : (wb_off + 8192u);                 \
  } while (0)

#define CHUNK_END() rb_off = (rb_off == 16384u) ? 0u : (rb_off + 8192u)

__global__ __launch_bounds__(512, 4) void mlp_kernel(
    const unsigned short* __restrict__ aevb,
    const unsigned short* __restrict__ pAll, const unsigned short* __restrict__ pPar,
    float* __restrict__ out) {
  __shared__ alignas(16) unsigned short stage[3][4096]; // 24576 B, 3 chunk buffers
  __shared__ alignas(16) __bf16 hbuf[8][16][168];       // 43008 B, wave-private
  __shared__ alignas(16) unsigned short hpar[MPB * 512]; // 4096 B
  // total LDS = 71680 B -> 2 blocks/CU -> 16 waves/CU

  // XCD-aware swizzle (784 % 8 == 0)
  const int nwg = NSP * BPS * MSPLIT;
  const int cpx = nwg / 8;
  const int blk = (blockIdx.x % 8) * cpx + blockIdx.x / 8;
  const int s = blk / (BPS * MSPLIT);
  const int rem = blk - s * (BPS * MSPLIT);
  const int mh = rem / BPS;          // model half: models mh*4 .. mh*4+3
  const int sb = rem - mh * BPS;     // atom block within species
  const int tid = threadIdx.x;
  const int w = tid >> 6;            // wave 0..7
  const int l = tid & 63;
  const int l15 = l & 15;
  const int l4 = l >> 4;

  // ---- stage this block's 4 model param records into LDS (256 int4) ----
  if (tid < 256) {
    const int4* src = (const int4*)(pPar + ((size_t)(s * NMODELS + mh * MPB)) * 512);
    ((int4*)hpar)[tid] = src[tid];
  }

  // per-wave weight-stream source: wave w owns frag w (1KB) of each 8KB chunk
  const size_t smBase = (size_t)(s * NMODELS + mh * MPB) * FRAGS_SM;
  const char* wsrc = (const char*)pAll + smBase * 1024 + (size_t)w * 1024 + (size_t)l * 16;

  // ---- A1 fragments: 1 M-tile (16 atoms) x 12 K-frags per wave ----
  bf16x8 a1[12];
  {
    int row = s * NPAD + sb * ABLK + w * 16 + l15;  // pad rows are zeros
    const bf16x8* rp = (const bf16x8*)(aevb + (size_t)row * D0 + l4 * 8);
#pragma unroll
    for (int kf = 0; kf < 12; ++kf) a1[kf] = rp[kf * 4];
  }

  const __bf16* hb = (const __bf16*)hpar;
  float acc4[4] = {0.f, 0.f, 0.f, 0.f};
  float bbacc = 0.f;

  __syncthreads(); // hpar visible; a1/hpar loads drained; vmem queue empty

  // ---- pipeline prologue: chunks 0,1 in flight ----
  int tn = 2;
  unsigned rb_off = 0, wb_off = 16384u;
  gload16(wsrc, (char*)stage + w * 1024);
  gload16(wsrc + 8192, (char*)stage + 8192 + w * 1024);

  // Model loop rolled; stream state (tn, rb_off, wb_off) loop-carried.
#pragma unroll 1
  for (int m = 0; m < MPB; ++m) {
    // One accumulator array reused by all three MFMA layers.
    f32x4 C[10];

    // ===== Layer 1: [16,384] x [384,160], 15 chunks of 8 frags =====
#pragma unroll
    for (int nt = 0; nt < 10; ++nt) {
      f32x4 z; z[0] = z[1] = z[2] = z[3] = 0.f; C[nt] = z;
    }
#pragma unroll
    for (int c = 0; c < 15; ++c) {
      CHUNK_HDR();
      const bf16x8* sbuf = (const bf16x8*)((const char*)stage + rb_off);
#pragma unroll
      for (int j = 0; j < 8; ++j) {
        const int f = c * 8 + j;    // kf = f/10, nt = f%10 (compile-time)
        bf16x8 b = sbuf[j * 64 + l];
        C[f % 10] = MFMA16(a1[f / 10], b, C[f % 10]);
      }
      CHUNK_END();
    }
    // bias + celu -> hbuf (row=atom 0..15, col=feature 0..159); bias via LDS
#pragma unroll
    for (int nt = 0; nt < 10; ++nt) {
      float bias = (float)hb[m * 512 + nt * 16 + l15];
#pragma unroll
      for (int r = 0; r < 4; ++r)
        hbuf[w][l4 * 4 + r][nt * 16 + l15] = (__bf16)celu01(C[nt][r] + bias);
    }

    // ===== Layer 2: [16,160] x [160,128], 5 chunks (kf = lc, nt = j) =====
    bf16x8 a2[5];
#pragma unroll
    for (int kf = 0; kf < 5; ++kf)
      a2[kf] = *(const bf16x8*)&hbuf[w][l15][kf * 32 + l4 * 8];

#pragma unroll
    for (int nt = 0; nt < 8; ++nt) {
      f32x4 z; z[0] = z[1] = z[2] = z[3] = 0.f; C[nt] = z;
    }
#pragma unroll
    for (int lc = 0; lc < 5; ++lc) {
      CHUNK_HDR();
      const bf16x8* sbuf = (const bf16x8*)((const char*)stage + rb_off);
#pragma unroll
      for (int j = 0; j < 8; ++j) {
        bf16x8 b = sbuf[j * 64 + l];
        C[j] = MFMA16(a2[lc], b, C[j]);
      }
      CHUNK_END();
    }
#pragma unroll
    for (int nt = 0; nt < 8; ++nt) {
      float bias = (float)hb[m * 512 + 160 + nt * 16 + l15];
#pragma unroll
      for (int r = 0; r < 4; ++r)
        hbuf[w][l4 * 4 + r][nt * 16 + l15] = (__bf16)celu01(C[nt][r] + bias);
    }

    // ===== Layer 3: [16,128] x [128,96], 3 chunks (kf = f/6, nt = f%6) =====
    bf16x8 a3[4];
#pragma unroll
    for (int kf = 0; kf < 4; ++kf)
      a3[kf] = *(const bf16x8*)&hbuf[w][l15][kf * 32 + l4 * 8];

#pragma unroll
    for (int nt = 0; nt < 6; ++nt) {
      f32x4 z; z[0] = z[1] = z[2] = z[3] = 0.f; C[nt] = z;
    }
#pragma unroll
    for (int lc = 0; lc < 3; ++lc) {
      CHUNK_HDR();
      const bf16x8* sbuf = (const bf16x8*)((const char*)stage + rb_off);
#pragma unroll
      for (int j = 0; j < 8; ++j) {
        const int f = lc * 8 + j;
        bf16x8 b = sbuf[j * 64 + l];
        C[f % 6] = MFMA16(a3[f / 6], b, C[f % 6]);
      }
      CHUNK_END();
    }

    // ===== Layer 4: celu(h3) . W4 + b4, all params from LDS =====
    float e[4] = {0.f, 0.f, 0.f, 0.f};
#pragma unroll
    for (int nt = 0; nt < 6; ++nt) {
      float b3v = (float)hb[m * 512 + 288 + nt * 16 + l15];
      float w4v = (float)hb[m * 512 + 384 + nt * 16 + l15];
#pragma unroll
      for (int r = 0; r < 4; ++r)
        e[r] += celu01(C[nt][r] + b3v) * w4v;
    }
#pragma unroll
    for (int r = 0; r < 4; ++r) acc4[r] += e[r];
    bbacc += ((const float*)hpar)[m * 256 + 240]; // b4 (f32 bits at shorts 480/481)
  } // models

  asm volatile("s_waitcnt vmcnt(0)" ::: "memory"); // drain leftover prefetches

  // ---- final: 16-lane reduce over features, mask pads, model-mean, atomic ----
  float tot = 0.f;
#pragma unroll
  for (int r = 0; r < 4; ++r) {
    float v = acc4[r];
    v += __shfl_xor(v, 1);
    v += __shfl_xor(v, 2);
    v += __shfl_xor(v, 4);
    v += __shfl_xor(v, 8);
    int slot = sb * ABLK + w * 16 + l4 * 4 + r;
    if (l15 == 0 && slot < NPER) tot += v + bbacc;
  }
  tot *= (1.f / NMODELS);
#pragma unroll
  for (int off = 1; off < 64; off <<= 1) tot += __shfl_xor(tot, off);
  if (l == 0) atomicAdd(out, tot);
}

extern "C" void kernel_launch(void* const* d_in, const int* in_sizes, int n_in,
                              void* d_out, int out_size, void* d_ws, size_t ws_size,
                              hipStream_t stream) {
  (void)in_sizes; (void)n_in; (void)out_size; (void)ws_size;
  const int* species = (const int*)d_in[0];
  const float* aev = (const float*)d_in[1];
  const float* W1 = (const float*)d_in[2];
  const float* b1 = (const float*)d_in[3];
  const float* W2 = (const float*)d_in[4];
  const float* b2 = (const float*)d_in[5];
  const float* W3 = (const float*)d_in[6];
  const float* b3 = (const float*)d_in[7];
  const float* W4 = (const float*)d_in[8];
  const float* b4 = (const float*)d_in[9];
  float* out = (float*)d_out;
  char* ws = (char*)d_ws;

  unsigned short* pAll = (unsigned short*)ws;
  unsigned short* pPar = (unsigned short*)(ws + PBIAS_OFF);
  int* order = (int*)(ws + ORDER_OFF);
  int* bcnt = (int*)(ws + BCNT_OFF);
  int* bpfx = (int*)(ws + BPFX_OFF);
  int* base = (int*)(ws + BASE_OFF);
  unsigned short* aevb = (unsigned short*)(ws + AEVB_OFF);

  hipMemsetAsync(d_out, 0, sizeof(float), stream);

  count_kernel<<<NRBLK, 256, 0, stream>>>(species, bcnt);
  scan_kernel<<<1, 256, 0, stream>>>(bcnt, bpfx, base);
  route_kernel<<<NRBLK, 256, 0, stream>>>(species, bpfx, base, order);

  {
    int total = NSP * NPAD * (D0 / 8);  // 2,408,448 threads
    aev_pack<<<total / 256, 256, 0, stream>>>(aev, order, aevb);
  }
  {
    int total = NSP * NMODELS * D0 * D1 / 2;
    pack_kernel<<<(total + 255) / 256, 256, 0, stream>>>(W1, (unsigned*)pAll, D0, D1, D1 / 16, 0, total);
  }
  {
    int total = NSP * NMODELS * D1 * D2 / 2;
    pack_kernel<<<(total + 255) / 256, 256, 0, stream>>>(W2, (unsigned*)pAll, D1, D2, D2 / 16, 120, total);
  }
  {
    int total = NSP * NMODELS * D2 * D3 / 2;
    pack_kernel<<<(total + 255) / 256, 256, 0, stream>>>(W3, (unsigned*)pAll, D2, D3, D3 / 16, 160, total);
  }
  {
    int total = NSP * NMODELS * 512;
    param_pack<<<(total + 255) / 256, 256, 0, stream>>>(b1, b2, b3, W4, b4, pPar);
  }

  mlp_kernel<<<NSP * BPS * MSPLIT, 512, 0, stream>>>(aevb, pAll, pPar, out);
}

// Round 12
// 206.779 us; speedup vs baseline: 1.2120x; 1.2120x over previous
//
#include <hip/hip_runtime.h>

// BmmEnsemble: species-routed 4x8 MLP ensemble (384->160->128->96->1, CELU 0.1),
// mean over 8 models, global sum -> scalar.
// R17: DE-SYNC THE WEIGHT STREAMS. R16 doubled waves/CU (occ 18->34%) with
// NO speedup => latency floor is wave-count-independent. The invariant in
// every ~215us variant: all ~64 concurrent blocks per XCD read the SAME
// weight stream at the SAME position in lockstep (XCD swizzle gives all 98
// blocks one (s,mh) stream; identical pacing) -> 64 duplicate requests per
// cache line on a ~16-channel subset of L2 per chunk ~ 2000cy serialization
// ~ the measured 1815cy/CU-slot. R14 doesn't falsify: its random units
// de-duped positions but blew the XCD working set to 23MB > 4MB L2 (FETCH
// 80MB, slower). Fix that keeps L2 residency (736KB/XCD): rotate each
// block's MODEL start m0=(blockIdx>>3)&3 -> cohort per stream position
// drops 64->16. Models independent; only per-block accumulation order
// changes (rounding-level; atomics already unordered). Everything else =
// R12 (best, 213us): 92 x 8KB chunk slots, counted vmcnt(2) + raw barrier,
// no pins, aevb routed-bf16 atoms, 2 blocks/CU.

#define NSP 4
#define NMODELS 8
#define MSPLIT 2
#define MPB (NMODELS / MSPLIT)       // 4 models per block
#define NATOMS 50000
#define NPER (NATOMS / NSP)          // 12500
#define NPAD 12544                   // 98*128 padded rows per species
#define D0 384
#define D1 160
#define D2 128
#define D3 96
#define NRBLK ((NATOMS + 255) / 256) // 196
#define ABLK 128
#define BPS ((NPER + ABLK - 1) / ABLK) // 98 blocks per species
#define FRAGS_SM 184                  // 120 (W1) + 40 (W2) + 24 (W3) fragments
#define CHUNKS_M 23                   // 184 frags / 8 per chunk
#define TOT_CHUNKS (MPB * CHUNKS_M)   // 92 chunks per block

typedef float f32x4 __attribute__((ext_vector_type(4)));
typedef __bf16 bf16x8 __attribute__((ext_vector_type(8)));

#define MFMA16(a, b, c) __builtin_amdgcn_mfma_f32_16x16x32_bf16((a), (b), (c), 0, 0, 0)

// ---- workspace layout (bytes) ----
#define PALL_BYTES ((size_t)NSP * NMODELS * FRAGS_SM * 1024)
#define PBIAS_OFF PALL_BYTES
#define PBIAS_BYTES ((size_t)NSP * NMODELS * 512 * 2)   // 1KB per (s,m)
#define ORDER_OFF (PBIAS_OFF + PBIAS_BYTES)
#define BCNT_OFF (ORDER_OFF + (size_t)NATOMS * 4)
#define BPFX_OFF (BCNT_OFF + (size_t)NRBLK * NSP * 4)
#define BASE_OFF (BPFX_OFF + (size_t)NRBLK * NSP * 4)
#define AEVB_OFF (BASE_OFF + 1024)                      // 64B-aligned
#define AEVB_BYTES ((size_t)NSP * NPAD * D0 * 2)        // 38.5 MB bf16

static __device__ __forceinline__ unsigned short bfbits(float f) {
  __bf16 h = (__bf16)f;
  return __builtin_bit_cast(unsigned short, h);
}

static __device__ __forceinline__ float celu01(float x) {
  // celu(x, alpha=0.1) = max(x,0) + min(0, 0.1*(exp(x/0.1)-1))
  return fmaxf(x, 0.f) + 0.1f * fminf(0.f, __expf(x * 10.f) - 1.f);
}

// async global->LDS, 16 B per lane; LDS dest = wave-uniform base + lane*16
static __device__ __forceinline__ void gload16(const void* g, void* l) {
  __builtin_amdgcn_global_load_lds(
      (const __attribute__((address_space(1))) unsigned int*)g,
      (__attribute__((address_space(3))) unsigned int*)l, 16, 0, 0);
}

// ---------------- routing ----------------
__global__ __launch_bounds__(256) void count_kernel(const int* __restrict__ species,
                                                    int* __restrict__ bcnt) {
  __shared__ int cnt[NSP];
  int t = threadIdx.x;
  if (t < NSP) cnt[t] = 0;
  __syncthreads();
  int i = blockIdx.x * 256 + t;
  if (i < NATOMS) atomicAdd(&cnt[species[i]], 1);
  __syncthreads();
  if (t < NSP) bcnt[blockIdx.x * NSP + t] = cnt[t];
}

__global__ __launch_bounds__(256) void scan_kernel(const int* __restrict__ bcnt,
                                                   int* __restrict__ bpfx,
                                                   int* __restrict__ base) {
  int w = threadIdx.x >> 6;
  int lane = threadIdx.x & 63;
  __shared__ int totals[NSP];
  int carry = 0;
  for (int c = 0; c < (NRBLK + 63) / 64; ++c) {
    int idx = c * 64 + lane;
    int v = (idx < NRBLK) ? bcnt[idx * NSP + w] : 0;
    int incl = v;
    for (int off = 1; off < 64; off <<= 1) {
      int tv = __shfl_up(incl, off);
      if (lane >= off) incl += tv;
    }
    if (idx < NRBLK) bpfx[idx * NSP + w] = carry + incl - v;
    carry += __shfl(incl, 63);
  }
  if (lane == 0) totals[w] = carry;
  __syncthreads();
  if (threadIdx.x == 0) {
    int run = 0;
    for (int s = 0; s < NSP; ++s) { base[s] = run; run += totals[s]; }
  }
}

__global__ __launch_bounds__(256) void route_kernel(const int* __restrict__ species,
                                                    const int* __restrict__ bpfx,
                                                    const int* __restrict__ base,
                                                    int* __restrict__ order) {
  __shared__ int sp[256];
  int t = threadIdx.x;
  int i = blockIdx.x * 256 + t;
  sp[t] = (i < NATOMS) ? species[i] : -1;
  __syncthreads();
  if (i < NATOMS) {
    int s = sp[t];
    int rank = 0;
    for (int j = 0; j < t; ++j) rank += (sp[j] == s) ? 1 : 0;
    order[base[s] + bpfx[blockIdx.x * NSP + s] + rank] = i;
  }
}

// ---------------- routed bf16 aev pre-pack ----------------
// aevb[s*NPAD + slot][k] = bf16(aev[order[s*NPER+slot]][k]); pad rows zeroed.
__global__ __launch_bounds__(256) void aev_pack(const float* __restrict__ aev,
                                                const int* __restrict__ order,
                                                unsigned short* __restrict__ aevb) {
  int tid = blockIdx.x * 256 + threadIdx.x;   // NSP*NPAD*48 total
  const int perRow = D0 / 8;                  // 48
  int row = tid / perRow;
  int seg = tid - row * perRow;
  if (row >= NSP * NPAD) return;
  int s = row / NPAD;
  int slot = row - s * NPAD;
  unsigned short o[8];
  if (slot < NPER) {
    int src = order[s * NPER + slot];
    const float4* q = (const float4*)(aev + (size_t)src * D0 + seg * 8);
    float4 v0 = q[0], v1 = q[1];
    o[0] = bfbits(v0.x); o[1] = bfbits(v0.y); o[2] = bfbits(v0.z); o[3] = bfbits(v0.w);
    o[4] = bfbits(v1.x); o[5] = bfbits(v1.y); o[6] = bfbits(v1.z); o[7] = bfbits(v1.w);
  } else {
#pragma unroll
    for (int e = 0; e < 8; ++e) o[e] = 0;
  }
  *(int4*)(aevb + (size_t)row * D0 + seg * 8) = *(const int4*)o;
}

// ---------------- weight pre-pack into contiguous B-fragment stream ----------------
// pAll: per (s,m) block of FRAGS_SM fragments (1 KB each). Frag order within a
// layer: f = kf*NT + nt. Lane l, bf16 elem e: k = kf*32 + 8*(l>>4) + e ; n = nt*16 + (l&15).
__global__ __launch_bounds__(256) void pack_kernel(const float* __restrict__ W,
                                                   unsigned* __restrict__ dst,
                                                   int K, int N, int NT, int fragBase,
                                                   int total) {
  int tid = blockIdx.x * 256 + threadIdx.x;
  if (tid >= total) return;
  int per_sm = K * N / 2;            // dwords per (s,m)
  int smi = tid / per_sm;
  int rem = tid - smi * per_sm;
  int frag = rem >> 8;               // 256 dwords per fragment
  int wi = rem & 255;
  int l = wi >> 2, d = wi & 3;
  int kf = frag / NT;
  int nt = frag - kf * NT;
  int k = kf * 32 + ((l >> 4) << 3) + 2 * d;
  int n = nt * 16 + (l & 15);
  const float* p = W + ((size_t)smi * K + k) * N + n;
  unsigned lo = bfbits(p[0]);
  unsigned hi = bfbits(p[N]);
  dst[((size_t)smi * FRAGS_SM + fragBase + frag) * 256 + wi] = lo | (hi << 16);
}

// param pack: per (s,m) record of 512 shorts:
// [0:160) b1 bf16 | [160:288) b2 bf16 | [288:384) b3 bf16 | [384:480) W4 bf16 |
// [480:482) b4 as f32 bit halves | rest 0
__global__ __launch_bounds__(256) void param_pack(const float* __restrict__ b1,
                                                  const float* __restrict__ b2,
                                                  const float* __restrict__ b3,
                                                  const float* __restrict__ W4,
                                                  const float* __restrict__ b4,
                                                  unsigned short* __restrict__ dst) {
  int i = blockIdx.x * 256 + threadIdx.x;
  if (i >= NSP * NMODELS * 512) return;
  int smi = i >> 9, o = i & 511;
  unsigned short v = 0;
  if (o < 160) v = bfbits(b1[smi * 160 + o]);
  else if (o < 288) v = bfbits(b2[smi * 128 + (o - 160)]);
  else if (o < 384) v = bfbits(b3[smi * 96 + (o - 288)]);
  else if (o < 480) v = bfbits(W4[smi * 96 + (o - 384)]);
  else if (o < 482) {
    unsigned u = __builtin_bit_cast(unsigned, b4[smi]);
    v = (unsigned short)((o == 480) ? (u & 0xffffu) : (u >> 16));
  }
  dst[i] = v;
}

// ---------------- fused MLP ----------------
// steady state: wait vmcnt(2) [chunk t's 2 loads done; t+1's 2 in flight],
// raw barrier (all waves' chunk-t loads landed), issue chunk t+2. tn walks
// the 92-chunk ring starting at this block's rotated model offset.
#define CHUNK_HDR()                                                      \
  do {                                                                   \
    asm volatile("s_waitcnt vmcnt(2)" ::: "memory");                     \
    __builtin_amdgcn_s_barrier();                                        \
    const char* _src = wsrc + (size_t)tn * 8192;                         \
    char* _d = (char*)stage + wb_off + w * 2048;                         \
    gload16(_src, _d);                                                   \
    gload16(_src + 1024, _d + 1024);                                     \
    tn = (tn + 1 == TOT_CHUNKS) ? 0 : (tn + 1);                          \
    wb_off = (wb_off == 16384u) ? 0u : (wb_off + 8192u);                 \
  } while (0)

#define CHUNK_END() rb_off = (rb_off == 16384u) ? 0u : (rb_off + 8192u)

__global__ __launch_bounds__(256, 2) void mlp_kernel(
    const unsigned short* __restrict__ aevb,
    const unsigned short* __restrict__ pAll, const unsigned short* __restrict__ pPar,
    float* __restrict__ out) {
  __shared__ alignas(16) unsigned short stage[3][4096]; // 24576 B, 3 chunk buffers
  __shared__ alignas(16) __bf16 hbuf[4][32][168];       // 43008 B, padded rows
  __shared__ alignas(16) unsigned short hpar[MPB * 512]; // 4096 B
  // total LDS = 71680 B -> 2 blocks/CU

  // XCD-aware swizzle (784 % 8 == 0): each XCD gets 98 consecutive blocks,
  // all sharing one (species, model-half) weight stream (736 KB) in its L2.
  const int nwg = NSP * BPS * MSPLIT;
  const int cpx = nwg / 8;
  const int blk = (blockIdx.x % 8) * cpx + blockIdx.x / 8;
  const int s = blk / (BPS * MSPLIT);
  const int rem = blk - s * (BPS * MSPLIT);
  const int mh = rem / BPS;          // model half: models mh*4 .. mh*4+3
  const int sb = rem - mh * BPS;     // atom block within species
  // model-start rotation: consecutive same-XCD blocks get different m0,
  // de-synchronizing their weight-stream positions (cohort 64 -> 16).
  const int m0 = (blockIdx.x >> 3) & 3;
  const int tid = threadIdx.x;
  const int w = tid >> 6;
  const int l = tid & 63;
  const int l15 = l & 15;
  const int l4 = l >> 4;

  // ---- stage this block's 4 model param records into LDS (256 int4) ----
  {
    const int4* src = (const int4*)(pPar + ((size_t)(s * NMODELS + mh * MPB)) * 512);
    ((int4*)hpar)[tid] = src[tid];
  }

  // per-wave weight-stream source pointer (per-lane address)
  const size_t smBase = (size_t)(s * NMODELS + mh * MPB) * FRAGS_SM;
  const char* wsrc = (const char*)pAll + smBase * 1024 + (size_t)w * 2048 + (size_t)l * 16;

  // ---- A1 fragments: routed bf16, fully coalesced, no converts ----
  bf16x8 a1[2][12];
#pragma unroll
  for (int mt = 0; mt < 2; ++mt) {
    int row = s * NPAD + sb * ABLK + w * 32 + mt * 16 + l15; // pad rows are zeros
    const bf16x8* rp = (const bf16x8*)(aevb + (size_t)row * D0 + l4 * 8);
#pragma unroll
    for (int kf = 0; kf < 12; ++kf) a1[mt][kf] = rp[kf * 4];
  }

  const __bf16* hb = (const __bf16*)hpar;
  float acc4[2][4] = {{0.f, 0.f, 0.f, 0.f}, {0.f, 0.f, 0.f, 0.f}};
  float bbacc = 0.f;

  __syncthreads(); // hpar visible; a1 loads drained; vmem queue empty below

  // ---- pipeline prologue: first two chunks of the ROTATED ring in flight
  // (c0 = m0*23 <= 69, so no wrap in the prologue) ----
  const int c0 = m0 * CHUNKS_M;
  int tn = c0 + 2;
  unsigned rb_off = 0, wb_off = 16384u;
  {
    char* d0 = (char*)stage + w * 2048;
    const char* s0 = wsrc + (size_t)c0 * 8192;
    gload16(s0, d0);
    gload16(s0 + 1024, d0 + 1024);
    char* d1 = (char*)stage + 8192 + w * 2048;
    const char* s1 = wsrc + (size_t)(c0 + 1) * 8192;
    gload16(s1, d1);
    gload16(s1 + 1024, d1 + 1024);
  }

  // Model loop rolled, ROTATED: block computes models m0, m0+1, m0+2, m0+3
  // (mod 4). Stream state (tn, rb_off, wb_off) loop-carried.
#pragma unroll 1
  for (int mi = 0; mi < MPB; ++mi) {
    const int m = (m0 + mi) & 3;
    // One accumulator array reused by all three MFMA layers.
    f32x4 C[2][10];

    // ===== Layer 1: [32,384] x [384,160], 15 chunks of 8 frags =====
#pragma unroll
    for (int mt = 0; mt < 2; ++mt)
#pragma unroll
      for (int nt = 0; nt < 10; ++nt) {
        f32x4 z; z[0] = z[1] = z[2] = z[3] = 0.f; C[mt][nt] = z;
      }
#pragma unroll
    for (int c = 0; c < 15; ++c) {
      CHUNK_HDR();
      const bf16x8* sbuf = (const bf16x8*)((const char*)stage + rb_off);
#pragma unroll
      for (int j = 0; j < 8; ++j) {
        const int f = c * 8 + j;    // kf = f/10, nt = f%10 (compile-time)
        bf16x8 b = sbuf[j * 64 + l];
        C[0][f % 10] = MFMA16(a1[0][f / 10], b, C[0][f % 10]);
        C[1][f % 10] = MFMA16(a1[1][f / 10], b, C[1][f % 10]);
      }
      CHUNK_END();
    }
    // bias + celu -> hbuf (row=atom 0..31, col=feature 0..159); bias via LDS
#pragma unroll
    for (int nt = 0; nt < 10; ++nt) {
      float bias = (float)hb[m * 512 + nt * 16 + l15];
#pragma unroll
      for (int mt = 0; mt < 2; ++mt)
#pragma unroll
        for (int r = 0; r < 4; ++r)
          hbuf[w][mt * 16 + l4 * 4 + r][nt * 16 + l15] = (__bf16)celu01(C[mt][nt][r] + bias);
    }

    // ===== Layer 2: [32,160] x [160,128], 5 chunks (kf = lc, nt = j) =====
    bf16x8 a2[2][5];
#pragma unroll
    for (int mt = 0; mt < 2; ++mt)
#pragma unroll
      for (int kf = 0; kf < 5; ++kf)
        a2[mt][kf] = *(const bf16x8*)&hbuf[w][mt * 16 + l15][kf * 32 + l4 * 8];

#pragma unroll
    for (int mt = 0; mt < 2; ++mt)
#pragma unroll
      for (int nt = 0; nt < 8; ++nt) {
        f32x4 z; z[0] = z[1] = z[2] = z[3] = 0.f; C[mt][nt] = z;
      }
#pragma unroll
    for (int lc = 0; lc < 5; ++lc) {
      CHUNK_HDR();
      const bf16x8* sbuf = (const bf16x8*)((const char*)stage + rb_off);
#pragma unroll
      for (int j = 0; j < 8; ++j) {
        bf16x8 b = sbuf[j * 64 + l];
        C[0][j] = MFMA16(a2[0][lc], b, C[0][j]);
        C[1][j] = MFMA16(a2[1][lc], b, C[1][j]);
      }
      CHUNK_END();
    }
#pragma unroll
    for (int nt = 0; nt < 8; ++nt) {
      float bias = (float)hb[m * 512 + 160 + nt * 16 + l15];
#pragma unroll
      for (int mt = 0; mt < 2; ++mt)
#pragma unroll
        for (int r = 0; r < 4; ++r)
          hbuf[w][mt * 16 + l4 * 4 + r][nt * 16 + l15] = (__bf16)celu01(C[mt][nt][r] + bias);
    }

    // ===== Layer 3: [32,128] x [128,96], 3 chunks (kf = f/6, nt = f%6) =====
    bf16x8 a3[2][4];
#pragma unroll
    for (int mt = 0; mt < 2; ++mt)
#pragma unroll
      for (int kf = 0; kf < 4; ++kf)
        a3[mt][kf] = *(const bf16x8*)&hbuf[w][mt * 16 + l15][kf * 32 + l4 * 8];

#pragma unroll
    for (int mt = 0; mt < 2; ++mt)
#pragma unroll
      for (int nt = 0; nt < 6; ++nt) {
        f32x4 z; z[0] = z[1] = z[2] = z[3] = 0.f; C[mt][nt] = z;
      }
#pragma unroll
    for (int lc = 0; lc < 3; ++lc) {
      CHUNK_HDR();
      const bf16x8* sbuf = (const bf16x8*)((const char*)stage + rb_off);
#pragma unroll
      for (int j = 0; j < 8; ++j) {
        const int f = lc * 8 + j;
        bf16x8 b = sbuf[j * 64 + l];
        C[0][f % 6] = MFMA16(a3[0][f / 6], b, C[0][f % 6]);
        C[1][f % 6] = MFMA16(a3[1][f / 6], b, C[1][f % 6]);
      }
      CHUNK_END();
    }

    // ===== Layer 4: celu(h3) . W4 + b4, all params from LDS =====
    float e[2][4] = {{0.f, 0.f, 0.f, 0.f}, {0.f, 0.f, 0.f, 0.f}};
#pragma unroll
    for (int nt = 0; nt < 6; ++nt) {
      float b3v = (float)hb[m * 512 + 288 + nt * 16 + l15];
      float w4v = (float)hb[m * 512 + 384 + nt * 16 + l15];
#pragma unroll
      for (int mt = 0; mt < 2; ++mt)
#pragma unroll
        for (int r = 0; r < 4; ++r)
          e[mt][r] += celu01(C[mt][nt][r] + b3v) * w4v;
    }
#pragma unroll
    for (int mt = 0; mt < 2; ++mt)
#pragma unroll
      for (int r = 0; r < 4; ++r) acc4[mt][r] += e[mt][r];
    bbacc += ((const float*)hpar)[m * 256 + 240]; // b4 (f32 bits at shorts 480/481)
  } // models

  asm volatile("s_waitcnt vmcnt(0)" ::: "memory"); // drain leftover prefetches

  // ---- final: 16-lane reduce, mask pads, partial model-mean, atomic ----
  float tot = 0.f;
#pragma unroll
  for (int mt = 0; mt < 2; ++mt)
#pragma unroll
    for (int r = 0; r < 4; ++r) {
      float v = acc4[mt][r];
      v += __shfl_xor(v, 1);
      v += __shfl_xor(v, 2);
      v += __shfl_xor(v, 4);
      v += __shfl_xor(v, 8);
      int slot = sb * ABLK + w * 32 + mt * 16 + l4 * 4 + r;
      if (l15 == 0 && slot < NPER) tot += v + bbacc;
    }
  tot *= (1.f / NMODELS);
#pragma unroll
  for (int off = 1; off < 64; off <<= 1) tot += __shfl_xor(tot, off);
  if (l == 0) atomicAdd(out, tot);
}

extern "C" void kernel_launch(void* const* d_in, const int* in_sizes, int n_in,
                              void* d_out, int out_size, void* d_ws, size_t ws_size,
                              hipStream_t stream) {
  (void)in_sizes; (void)n_in; (void)out_size; (void)ws_size;
  const int* species = (const int*)d_in[0];
  const float* aev = (const float*)d_in[1];
  const float* W1 = (const float*)d_in[2];
  const float* b1 = (const float*)d_in[3];
  const float* W2 = (const float*)d_in[4];
  const float* b2 = (const float*)d_in[5];
  const float* W3 = (const float*)d_in[6];
  const float* b3 = (const float*)d_in[7];
  const float* W4 = (const float*)d_in[8];
  const float* b4 = (const float*)d_in[9];
  float* out = (float*)d_out;
  char* ws = (char*)d_ws;

  unsigned short* pAll = (unsigned short*)ws;
  unsigned short* pPar = (unsigned short*)(ws + PBIAS_OFF);
  int* order = (int*)(ws + ORDER_OFF);
  int* bcnt = (int*)(ws + BCNT_OFF);
  int* bpfx = (int*)(ws + BPFX_OFF);
  int* base = (int*)(ws + BASE_OFF);
  unsigned short* aevb = (unsigned short*)(ws + AEVB_OFF);

  hipMemsetAsync(d_out, 0, sizeof(float), stream);

  count_kernel<<<NRBLK, 256, 0, stream>>>(species, bcnt);
  scan_kernel<<<1, 256, 0, stream>>>(bcnt, bpfx, base);
  route_kernel<<<NRBLK, 256, 0, stream>>>(species, bpfx, base, order);

  {
    int total = NSP * NPAD * (D0 / 8);  // 2,408,448 threads
    aev_pack<<<total / 256, 256, 0, stream>>>(aev, order, aevb);
  }
  {
    int total = NSP * NMODELS * D0 * D1 / 2;
    pack_kernel<<<(total + 255) / 256, 256, 0, stream>>>(W1, (unsigned*)pAll, D0, D1, D1 / 16, 0, total);
  }
  {
    int total = NSP * NMODELS * D1 * D2 / 2;
    pack_kernel<<<(total + 255) / 256, 256, 0, stream>>>(W2, (unsigned*)pAll, D1, D2, D2 / 16, 120, total);
  }
  {
    int total = NSP * NMODELS * D2 * D3 / 2;
    pack_kernel<<<(total + 255) / 256, 256, 0, stream>>>(W3, (unsigned*)pAll, D2, D3, D3 / 16, 160, total);
  }
  {
    int total = NSP * NMODELS * 512;
    param_pack<<<(total + 255) / 256, 256, 0, stream>>>(b1, b2, b3, W4, b4, pPar);
  }

  mlp_kernel<<<NSP * BPS * MSPLIT, 256, 0, stream>>>(aevb, pAll, pPar, out);
}

// Round 13
// 194.638 us; speedup vs baseline: 1.2876x; 1.0624x over previous
//
#include <hip/hip_runtime.h>

// BmmEnsemble: species-routed 4x8 MLP ensemble (384->160->128->96->1, CELU 0.1),
// mean over 8 models, global sum -> scalar.
// R18: SINGLE-GENERATION GRID (MSPLIT=1). R16 proved per-slot cost is nearly
// concurrency-free (2x waves -> no speedup; solo ~ paired pace) => the wall
// is paced by CUs running TWO sequential 92-slot generations (784 blocks on
// 512 residency slots), 184 sequential slot-times for 141 slot-times of
// work. Fix: fewer, longer blocks -- MSPLIT=1: 392 blocks x 184 slots, all
// resident in ONE generation; the co-resident partner rides the latency
// floor nearly free. Same total slots (72128), same slot structure; per-XCD
// stream = one species' 8-model 1.47MB (L2-resident). Bonus: model rotation
// now spans 8 models -> cohort ~24 -> ~6 (extends R17's proven -9us).
// Everything else identical to R17 (best, 204us): 8KB chunks, counted
// vmcnt(2) + raw barrier, no pins, aevb routed-bf16 atoms, XCD swizzle.

#define NSP 4
#define NMODELS 8
#define MPB NMODELS                  // all 8 models per block
#define NATOMS 50000
#define NPER (NATOMS / NSP)          // 12500
#define NPAD 12544                   // 98*128 padded rows per species
#define D0 384
#define D1 160
#define D2 128
#define D3 96
#define NRBLK ((NATOMS + 255) / 256) // 196
#define ABLK 128
#define BPS ((NPER + ABLK - 1) / ABLK) // 98 blocks per species
#define FRAGS_SM 184                  // 120 (W1) + 40 (W2) + 24 (W3) fragments
#define CHUNKS_M 23                   // 184 frags / 8 per chunk
#define TOT_CHUNKS (MPB * CHUNKS_M)   // 184 chunks per block

typedef float f32x4 __attribute__((ext_vector_type(4)));
typedef __bf16 bf16x8 __attribute__((ext_vector_type(8)));

#define MFMA16(a, b, c) __builtin_amdgcn_mfma_f32_16x16x32_bf16((a), (b), (c), 0, 0, 0)

// ---- workspace layout (bytes) ----
#define PALL_BYTES ((size_t)NSP * NMODELS * FRAGS_SM * 1024)
#define PBIAS_OFF PALL_BYTES
#define PBIAS_BYTES ((size_t)NSP * NMODELS * 512 * 2)   // 1KB per (s,m)
#define ORDER_OFF (PBIAS_OFF + PBIAS_BYTES)
#define BCNT_OFF (ORDER_OFF + (size_t)NATOMS * 4)
#define BPFX_OFF (BCNT_OFF + (size_t)NRBLK * NSP * 4)
#define BASE_OFF (BPFX_OFF + (size_t)NRBLK * NSP * 4)
#define AEVB_OFF (BASE_OFF + 1024)                      // 64B-aligned
#define AEVB_BYTES ((size_t)NSP * NPAD * D0 * 2)        // 38.5 MB bf16

static __device__ __forceinline__ unsigned short bfbits(float f) {
  __bf16 h = (__bf16)f;
  return __builtin_bit_cast(unsigned short, h);
}

static __device__ __forceinline__ float celu01(float x) {
  // celu(x, alpha=0.1) = max(x,0) + min(0, 0.1*(exp(x/0.1)-1))
  return fmaxf(x, 0.f) + 0.1f * fminf(0.f, __expf(x * 10.f) - 1.f);
}

// async global->LDS, 16 B per lane; LDS dest = wave-uniform base + lane*16
static __device__ __forceinline__ void gload16(const void* g, void* l) {
  __builtin_amdgcn_global_load_lds(
      (const __attribute__((address_space(1))) unsigned int*)g,
      (__attribute__((address_space(3))) unsigned int*)l, 16, 0, 0);
}

// ---------------- routing ----------------
__global__ __launch_bounds__(256) void count_kernel(const int* __restrict__ species,
                                                    int* __restrict__ bcnt) {
  __shared__ int cnt[NSP];
  int t = threadIdx.x;
  if (t < NSP) cnt[t] = 0;
  __syncthreads();
  int i = blockIdx.x * 256 + t;
  if (i < NATOMS) atomicAdd(&cnt[species[i]], 1);
  __syncthreads();
  if (t < NSP) bcnt[blockIdx.x * NSP + t] = cnt[t];
}

__global__ __launch_bounds__(256) void scan_kernel(const int* __restrict__ bcnt,
                                                   int* __restrict__ bpfx,
                                                   int* __restrict__ base) {
  int w = threadIdx.x >> 6;
  int lane = threadIdx.x & 63;
  __shared__ int totals[NSP];
  int carry = 0;
  for (int c = 0; c < (NRBLK + 63) / 64; ++c) {
    int idx = c * 64 + lane;
    int v = (idx < NRBLK) ? bcnt[idx * NSP + w] : 0;
    int incl = v;
    for (int off = 1; off < 64; off <<= 1) {
      int tv = __shfl_up(incl, off);
      if (lane >= off) incl += tv;
    }
    if (idx < NRBLK) bpfx[idx * NSP + w] = carry + incl - v;
    carry += __shfl(incl, 63);
  }
  if (lane == 0) totals[w] = carry;
  __syncthreads();
  if (threadIdx.x == 0) {
    int run = 0;
    for (int s = 0; s < NSP; ++s) { base[s] = run; run += totals[s]; }
  }
}

__global__ __launch_bounds__(256) void route_kernel(const int* __restrict__ species,
                                                    const int* __restrict__ bpfx,
                                                    const int* __restrict__ base,
                                                    int* __restrict__ order) {
  __shared__ int sp[256];
  int t = threadIdx.x;
  int i = blockIdx.x * 256 + t;
  sp[t] = (i < NATOMS) ? species[i] : -1;
  __syncthreads();
  if (i < NATOMS) {
    int s = sp[t];
    int rank = 0;
    for (int j = 0; j < t; ++j) rank += (sp[j] == s) ? 1 : 0;
    order[base[s] + bpfx[blockIdx.x * NSP + s] + rank] = i;
  }
}

// ---------------- routed bf16 aev pre-pack ----------------
// aevb[s*NPAD + slot][k] = bf16(aev[order[s*NPER+slot]][k]); pad rows zeroed.
__global__ __launch_bounds__(256) void aev_pack(const float* __restrict__ aev,
                                                const int* __restrict__ order,
                                                unsigned short* __restrict__ aevb) {
  int tid = blockIdx.x * 256 + threadIdx.x;   // NSP*NPAD*48 total
  const int perRow = D0 / 8;                  // 48
  int row = tid / perRow;
  int seg = tid - row * perRow;
  if (row >= NSP * NPAD) return;
  int s = row / NPAD;
  int slot = row - s * NPAD;
  unsigned short o[8];
  if (slot < NPER) {
    int src = order[s * NPER + slot];
    const float4* q = (const float4*)(aev + (size_t)src * D0 + seg * 8);
    float4 v0 = q[0], v1 = q[1];
    o[0] = bfbits(v0.x); o[1] = bfbits(v0.y); o[2] = bfbits(v0.z); o[3] = bfbits(v0.w);
    o[4] = bfbits(v1.x); o[5] = bfbits(v1.y); o[6] = bfbits(v1.z); o[7] = bfbits(v1.w);
  } else {
#pragma unroll
    for (int e = 0; e < 8; ++e) o[e] = 0;
  }
  *(int4*)(aevb + (size_t)row * D0 + seg * 8) = *(const int4*)o;
}

// ---------------- weight pre-pack into contiguous B-fragment stream ----------------
// pAll: per (s,m) block of FRAGS_SM fragments (1 KB each). Frag order within a
// layer: f = kf*NT + nt. Lane l, bf16 elem e: k = kf*32 + 8*(l>>4) + e ; n = nt*16 + (l&15).
__global__ __launch_bounds__(256) void pack_kernel(const float* __restrict__ W,
                                                   unsigned* __restrict__ dst,
                                                   int K, int N, int NT, int fragBase,
                                                   int total) {
  int tid = blockIdx.x * 256 + threadIdx.x;
  if (tid >= total) return;
  int per_sm = K * N / 2;            // dwords per (s,m)
  int smi = tid / per_sm;
  int rem = tid - smi * per_sm;
  int frag = rem >> 8;               // 256 dwords per fragment
  int wi = rem & 255;
  int l = wi >> 2, d = wi & 3;
  int kf = frag / NT;
  int nt = frag - kf * NT;
  int k = kf * 32 + ((l >> 4) << 3) + 2 * d;
  int n = nt * 16 + (l & 15);
  const float* p = W + ((size_t)smi * K + k) * N + n;
  unsigned lo = bfbits(p[0]);
  unsigned hi = bfbits(p[N]);
  dst[((size_t)smi * FRAGS_SM + fragBase + frag) * 256 + wi] = lo | (hi << 16);
}

// param pack: per (s,m) record of 512 shorts:
// [0:160) b1 bf16 | [160:288) b2 bf16 | [288:384) b3 bf16 | [384:480) W4 bf16 |
// [480:482) b4 as f32 bit halves | rest 0
__global__ __launch_bounds__(256) void param_pack(const float* __restrict__ b1,
                                                  const float* __restrict__ b2,
                                                  const float* __restrict__ b3,
                                                  const float* __restrict__ W4,
                                                  const float* __restrict__ b4,
                                                  unsigned short* __restrict__ dst) {
  int i = blockIdx.x * 256 + threadIdx.x;
  if (i >= NSP * NMODELS * 512) return;
  int smi = i >> 9, o = i & 511;
  unsigned short v = 0;
  if (o < 160) v = bfbits(b1[smi * 160 + o]);
  else if (o < 288) v = bfbits(b2[smi * 128 + (o - 160)]);
  else if (o < 384) v = bfbits(b3[smi * 96 + (o - 288)]);
  else if (o < 480) v = bfbits(W4[smi * 96 + (o - 384)]);
  else if (o < 482) {
    unsigned u = __builtin_bit_cast(unsigned, b4[smi]);
    v = (unsigned short)((o == 480) ? (u & 0xffffu) : (u >> 16));
  }
  dst[i] = v;
}

// ---------------- fused MLP ----------------
// steady state: wait vmcnt(2) [chunk t's 2 loads done; t+1's 2 in flight],
// raw barrier (all waves' chunk-t loads landed), issue chunk t+2. tn walks
// the 184-chunk ring starting at this block's rotated model offset.
#define CHUNK_HDR()                                                      \
  do {                                                                   \
    asm volatile("s_waitcnt vmcnt(2)" ::: "memory");                     \
    __builtin_amdgcn_s_barrier();                                        \
    const char* _src = wsrc + (size_t)tn * 8192;                         \
    char* _d = (char*)stage + wb_off + w * 2048;                         \
    gload16(_src, _d);                                                   \
    gload16(_src + 1024, _d + 1024);                                     \
    tn = (tn + 1 == TOT_CHUNKS) ? 0 : (tn + 1);                          \
    wb_off = (wb_off == 16384u) ? 0u : (wb_off + 8192u);                 \
  } while (0)

#define CHUNK_END() rb_off = (rb_off == 16384u) ? 0u : (rb_off + 8192u)

__global__ __launch_bounds__(256, 2) void mlp_kernel(
    const unsigned short* __restrict__ aevb,
    const unsigned short* __restrict__ pAll, const unsigned short* __restrict__ pPar,
    float* __restrict__ out) {
  __shared__ alignas(16) unsigned short stage[3][4096]; // 24576 B, 3 chunk buffers
  __shared__ alignas(16) __bf16 hbuf[4][32][168];       // 43008 B, padded rows
  __shared__ alignas(16) unsigned short hpar[MPB * 512]; // 8192 B (8 models)
  // total LDS = 75776 B -> 2 blocks/CU

  // XCD-aware swizzle (392 % 8 == 0): each XCD gets 49 consecutive blocks;
  // 2 XCDs share one species' 8-model weight stream (1.47 MB, L2-resident).
  const int nwg = NSP * BPS;
  const int cpx = nwg / 8;
  const int blk = (blockIdx.x % 8) * cpx + blockIdx.x / 8;
  const int s = blk / BPS;
  const int sb = blk - s * BPS;      // atom block within species
  // model-start rotation over all 8 models: consecutive same-XCD blocks get
  // different m0 -> weight-stream positions spread across 8 phases.
  const int m0 = (blockIdx.x >> 3) & 7;
  const int tid = threadIdx.x;
  const int w = tid >> 6;
  const int l = tid & 63;
  const int l15 = l & 15;
  const int l4 = l >> 4;

  // ---- stage this block's 8 model param records into LDS (512 int4) ----
  {
    const int4* src = (const int4*)(pPar + (size_t)s * NMODELS * 512);
    ((int4*)hpar)[tid] = src[tid];
    ((int4*)hpar)[tid + 256] = src[tid + 256];
  }

  // per-wave weight-stream source pointer (per-lane address)
  const size_t smBase = (size_t)s * NMODELS * FRAGS_SM;
  const char* wsrc = (const char*)pAll + smBase * 1024 + (size_t)w * 2048 + (size_t)l * 16;

  // ---- A1 fragments: routed bf16, fully coalesced, no converts ----
  bf16x8 a1[2][12];
#pragma unroll
  for (int mt = 0; mt < 2; ++mt) {
    int row = s * NPAD + sb * ABLK + w * 32 + mt * 16 + l15; // pad rows are zeros
    const bf16x8* rp = (const bf16x8*)(aevb + (size_t)row * D0 + l4 * 8);
#pragma unroll
    for (int kf = 0; kf < 12; ++kf) a1[mt][kf] = rp[kf * 4];
  }

  const __bf16* hb = (const __bf16*)hpar;
  float acc4[2][4] = {{0.f, 0.f, 0.f, 0.f}, {0.f, 0.f, 0.f, 0.f}};
  float bbacc = 0.f;

  __syncthreads(); // hpar visible; a1 loads drained; vmem queue empty below

  // ---- pipeline prologue: first two chunks of the ROTATED ring in flight
  // (c0 = m0*23 <= 161, so no wrap in the prologue) ----
  const int c0 = m0 * CHUNKS_M;
  int tn = c0 + 2;
  unsigned rb_off = 0, wb_off = 16384u;
  {
    char* d0 = (char*)stage + w * 2048;
    const char* s0 = wsrc + (size_t)c0 * 8192;
    gload16(s0, d0);
    gload16(s0 + 1024, d0 + 1024);
    char* d1 = (char*)stage + 8192 + w * 2048;
    const char* s1 = wsrc + (size_t)(c0 + 1) * 8192;
    gload16(s1, d1);
    gload16(s1 + 1024, d1 + 1024);
  }

  // Model loop rolled, ROTATED: block computes models m0, m0+1, ..., m0+7
  // (mod 8). Stream state (tn, rb_off, wb_off) loop-carried.
#pragma unroll 1
  for (int mi = 0; mi < MPB; ++mi) {
    const int m = (m0 + mi) & 7;
    // One accumulator array reused by all three MFMA layers.
    f32x4 C[2][10];

    // ===== Layer 1: [32,384] x [384,160], 15 chunks of 8 frags =====
#pragma unroll
    for (int mt = 0; mt < 2; ++mt)
#pragma unroll
      for (int nt = 0; nt < 10; ++nt) {
        f32x4 z; z[0] = z[1] = z[2] = z[3] = 0.f; C[mt][nt] = z;
      }
#pragma unroll
    for (int c = 0; c < 15; ++c) {
      CHUNK_HDR();
      const bf16x8* sbuf = (const bf16x8*)((const char*)stage + rb_off);
#pragma unroll
      for (int j = 0; j < 8; ++j) {
        const int f = c * 8 + j;    // kf = f/10, nt = f%10 (compile-time)
        bf16x8 b = sbuf[j * 64 + l];
        C[0][f % 10] = MFMA16(a1[0][f / 10], b, C[0][f % 10]);
        C[1][f % 10] = MFMA16(a1[1][f / 10], b, C[1][f % 10]);
      }
      CHUNK_END();
    }
    // bias + celu -> hbuf (row=atom 0..31, col=feature 0..159); bias via LDS
#pragma unroll
    for (int nt = 0; nt < 10; ++nt) {
      float bias = (float)hb[m * 512 + nt * 16 + l15];
#pragma unroll
      for (int mt = 0; mt < 2; ++mt)
#pragma unroll
        for (int r = 0; r < 4; ++r)
          hbuf[w][mt * 16 + l4 * 4 + r][nt * 16 + l15] = (__bf16)celu01(C[mt][nt][r] + bias);
    }

    // ===== Layer 2: [32,160] x [160,128], 5 chunks (kf = lc, nt = j) =====
    bf16x8 a2[2][5];
#pragma unroll
    for (int mt = 0; mt < 2; ++mt)
#pragma unroll
      for (int kf = 0; kf < 5; ++kf)
        a2[mt][kf] = *(const bf16x8*)&hbuf[w][mt * 16 + l15][kf * 32 + l4 * 8];

#pragma unroll
    for (int mt = 0; mt < 2; ++mt)
#pragma unroll
      for (int nt = 0; nt < 8; ++nt) {
        f32x4 z; z[0] = z[1] = z[2] = z[3] = 0.f; C[mt][nt] = z;
      }
#pragma unroll
    for (int lc = 0; lc < 5; ++lc) {
      CHUNK_HDR();
      const bf16x8* sbuf = (const bf16x8*)((const char*)stage + rb_off);
#pragma unroll
      for (int j = 0; j < 8; ++j) {
        bf16x8 b = sbuf[j * 64 + l];
        C[0][j] = MFMA16(a2[0][lc], b, C[0][j]);
        C[1][j] = MFMA16(a2[1][lc], b, C[1][j]);
      }
      CHUNK_END();
    }
#pragma unroll
    for (int nt = 0; nt < 8; ++nt) {
      float bias = (float)hb[m * 512 + 160 + nt * 16 + l15];
#pragma unroll
      for (int mt = 0; mt < 2; ++mt)
#pragma unroll
        for (int r = 0; r < 4; ++r)
          hbuf[w][mt * 16 + l4 * 4 + r][nt * 16 + l15] = (__bf16)celu01(C[mt][nt][r] + bias);
    }

    // ===== Layer 3: [32,128] x [128,96], 3 chunks (kf = f/6, nt = f%6) =====
    bf16x8 a3[2][4];
#pragma unroll
    for (int mt = 0; mt < 2; ++mt)
#pragma unroll
      for (int kf = 0; kf < 4; ++kf)
        a3[mt][kf] = *(const bf16x8*)&hbuf[w][mt * 16 + l15][kf * 32 + l4 * 8];

#pragma unroll
    for (int mt = 0; mt < 2; ++mt)
#pragma unroll
      for (int nt = 0; nt < 6; ++nt) {
        f32x4 z; z[0] = z[1] = z[2] = z[3] = 0.f; C[mt][nt] = z;
      }
#pragma unroll
    for (int lc = 0; lc < 3; ++lc) {
      CHUNK_HDR();
      const bf16x8* sbuf = (const bf16x8*)((const char*)stage + rb_off);
#pragma unroll
      for (int j = 0; j < 8; ++j) {
        const int f = lc * 8 + j;
        bf16x8 b = sbuf[j * 64 + l];
        C[0][f % 6] = MFMA16(a3[0][f / 6], b, C[0][f % 6]);
        C[1][f % 6] = MFMA16(a3[1][f / 6], b, C[1][f % 6]);
      }
      CHUNK_END();
    }

    // ===== Layer 4: celu(h3) . W4 + b4, all params from LDS =====
    float e[2][4] = {{0.f, 0.f, 0.f, 0.f}, {0.f, 0.f, 0.f, 0.f}};
#pragma unroll
    for (int nt = 0; nt < 6; ++nt) {
      float b3v = (float)hb[m * 512 + 288 + nt * 16 + l15];
      float w4v = (float)hb[m * 512 + 384 + nt * 16 + l15];
#pragma unroll
      for (int mt = 0; mt < 2; ++mt)
#pragma unroll
        for (int r = 0; r < 4; ++r)
          e[mt][r] += celu01(C[mt][nt][r] + b3v) * w4v;
    }
#pragma unroll
    for (int mt = 0; mt < 2; ++mt)
#pragma unroll
      for (int r = 0; r < 4; ++r) acc4[mt][r] += e[mt][r];
    bbacc += ((const float*)hpar)[m * 256 + 240]; // b4 (f32 bits at shorts 480/481)
  } // models

  asm volatile("s_waitcnt vmcnt(0)" ::: "memory"); // drain leftover prefetches

  // ---- final: 16-lane reduce, mask pads, full model-mean, atomic ----
  float tot = 0.f;
#pragma unroll
  for (int mt = 0; mt < 2; ++mt)
#pragma unroll
    for (int r = 0; r < 4; ++r) {
      float v = acc4[mt][r];
      v += __shfl_xor(v, 1);
      v += __shfl_xor(v, 2);
      v += __shfl_xor(v, 4);
      v += __shfl_xor(v, 8);
      int slot = sb * ABLK + w * 32 + mt * 16 + l4 * 4 + r;
      if (l15 == 0 && slot < NPER) tot += v + bbacc;
    }
  tot *= (1.f / NMODELS);
#pragma unroll
  for (int off = 1; off < 64; off <<= 1) tot += __shfl_xor(tot, off);
  if (l == 0) atomicAdd(out, tot);
}

extern "C" void kernel_launch(void* const* d_in, const int* in_sizes, int n_in,
                              void* d_out, int out_size, void* d_ws, size_t ws_size,
                              hipStream_t stream) {
  (void)in_sizes; (void)n_in; (void)out_size; (void)ws_size;
  const int* species = (const int*)d_in[0];
  const float* aev = (const float*)d_in[1];
  const float* W1 = (const float*)d_in[2];
  const float* b1 = (const float*)d_in[3];
  const float* W2 = (const float*)d_in[4];
  const float* b2 = (const float*)d_in[5];
  const float* W3 = (const float*)d_in[6];
  const float* b3 = (const float*)d_in[7];
  const float* W4 = (const float*)d_in[8];
  const float* b4 = (const float*)d_in[9];
  float* out = (float*)d_out;
  char* ws = (char*)d_ws;

  unsigned short* pAll = (unsigned short*)ws;
  unsigned short* pPar = (unsigned short*)(ws + PBIAS_OFF);
  int* order = (int*)(ws + ORDER_OFF);
  int* bcnt = (int*)(ws + BCNT_OFF);
  int* bpfx = (int*)(ws + BPFX_OFF);
  int* base = (int*)(ws + BASE_OFF);
  unsigned short* aevb = (unsigned short*)(ws + AEVB_OFF);

  hipMemsetAsync(d_out, 0, sizeof(float), stream);

  count_kernel<<<NRBLK, 256, 0, stream>>>(species, bcnt);
  scan_kernel<<<1, 256, 0, stream>>>(bcnt, bpfx, base);
  route_kernel<<<NRBLK, 256, 0, stream>>>(species, bpfx, base, order);

  {
    int total = NSP * NPAD * (D0 / 8);  // 2,408,448 threads
    aev_pack<<<total / 256, 256, 0, stream>>>(aev, order, aevb);
  }
  {
    int total = NSP * NMODELS * D0 * D1 / 2;
    pack_kernel<<<(total + 255) / 256, 256, 0, stream>>>(W1, (unsigned*)pAll, D0, D1, D1 / 16, 0, total);
  }
  {
    int total = NSP * NMODELS * D1 * D2 / 2;
    pack_kernel<<<(total + 255) / 256, 256, 0, stream>>>(W2, (unsigned*)pAll, D1, D2, D2 / 16, 120, total);
  }
  {
    int total = NSP * NMODELS * D2 * D3 / 2;
    pack_kernel<<<(total + 255) / 256, 256, 0, stream>>>(W3, (unsigned*)pAll, D2, D3, D3 / 16, 160, total);
  }
  {
    int total = NSP * NMODELS * 512;
    param_pack<<<(total + 255) / 256, 256, 0, stream>>>(b1, b2, b3, W4, b4, pPar);
  }

  mlp_kernel<<<NSP * BPS, 256, 0, stream>>>(aevb, pAll, pPar, out);
}